// Round 1
// 480.943 us; speedup vs baseline: 1.0062x; 1.0062x over previous
//
#include <hip/hip_runtime.h>
#include <hip/hip_bf16.h>

#define SS 2048
#define HH 512

typedef __attribute__((ext_vector_type(8))) short short8;
typedef __attribute__((ext_vector_type(4))) float f32x4;

__device__ __forceinline__ float bflo(unsigned u) { return __uint_as_float(u << 16); }
__device__ __forceinline__ float bfhi(unsigned u) { return __uint_as_float(u & 0xffff0000u); }

__device__ __forceinline__ short f2bf(float v) {
  __hip_bfloat16 h = __float2bfloat16(v);
  return *reinterpret_cast<short*>(&h);
}

__device__ __forceinline__ float tanh_fast(float x) {
  x = fminf(fmaxf(x, -15.f), 15.f);
  float e = __expf(2.f * x);
  return 1.f - 2.f / (e + 1.f);
}

// ---------------- dtype detector: 1 = inputs are bf16, 0 = fp32 ----------------
__global__ void k_detect(const unsigned* __restrict__ Eu, int* __restrict__ flag) {
  int lane = threadIdx.x;  // 64 threads
  unsigned w = Eu[(size_t)lane * 4097];
  unsigned e = (w >> 7) & 0xFF;  // exponent field of the low bf16 half
  bool inr = (e >= 90 && e <= 140);
  unsigned long long m = __ballot(inr);
  if (lane == 0) *flag = (__popcll(m) >= 48) ? 1 : 0;
}

// ---------------- W1 transpose -> bf16 W1T[d][h] = W1[h][d] ----------------
__global__ __launch_bounds__(256) void k_transpose(const __hip_bfloat16* __restrict__ W1b,
                                                   const float* __restrict__ W1f,
                                                   const int* __restrict__ flagp,
                                                   __hip_bfloat16* __restrict__ W1T) {
  const int mode = *flagp;
  __shared__ __hip_bfloat16 t[64][65];
  int r0 = blockIdx.y * 64, c0 = blockIdx.x * 64;
  for (int i = threadIdx.x; i < 4096; i += 256) {
    int r = i >> 6, c = i & 63;
    size_t idx = (size_t)(r0 + r) * HH + c0 + c;
    float v = mode ? (float)W1b[idx] : W1f[idx];
    t[r][c] = __float2bfloat16(v);
  }
  __syncthreads();
  for (int i = threadIdx.x; i < 4096; i += 256) {
    int r = i >> 6, c = i & 63;
    W1T[(size_t)(c0 + r) * HH + r0 + c] = t[c][r];
  }
}

// ---------------- qp_part[p][b][d] = sum_{h in part p} q[b][h] * W2[h][d] ----------------
// No atomics, no zero-init: each block writes its own 512-wide partial.
__global__ __launch_bounds__(256) void k_qp(const __hip_bfloat16* __restrict__ qb,
                                            const float* __restrict__ qf,
                                            const __hip_bfloat16* __restrict__ W2b,
                                            const float* __restrict__ W2f,
                                            const int* __restrict__ flagp,
                                            float* __restrict__ qp_part) {
  const int mode = *flagp;
  int b = blockIdx.x, p = blockIdx.y, h0 = p * 128;
  __shared__ float qs[128];
  if (threadIdx.x < 128) {
    size_t qi = (size_t)b * HH + h0 + threadIdx.x;
    qs[threadIdx.x] = mode ? (float)qb[qi] : qf[qi];
  }
  __syncthreads();
  int col = threadIdx.x * 2;
  float a0 = 0.f, a1 = 0.f;
  if (mode) {
#pragma unroll 4
    for (int i = 0; i < 128; ++i) {
      float qa = qs[i];
      unsigned u = *(const unsigned*)(W2b + (size_t)(h0 + i) * HH + col);
      a0 = fmaf(qa, bflo(u), a0);
      a1 = fmaf(qa, bfhi(u), a1);
    }
  } else {
#pragma unroll 4
    for (int i = 0; i < 128; ++i) {
      float qa = qs[i];
      float2 v = *(const float2*)(W2f + (size_t)(h0 + i) * HH + col);
      a0 = fmaf(qa, v.x, a0);
      a1 = fmaf(qa, v.y, a1);
    }
  }
  float* dst = qp_part + ((size_t)p * 64 + b) * HH + col;
  dst[0] = a0;
  dst[1] = a1;
}

// ---------------- fused energy: e[b][s] = V . tanh(E[b][s]*W1 + qp[b]) ----------------
// 128-row M-tile/WG; A frags resident in regs (short8 afr[2][16] = 128 VGPRs);
// B streamed via DOUBLE-BUFFERED 2x8KB LDS, register-prefetched one K-step ahead.
// One raw s_barrier per kt-step (lgkmcnt(0) only — the global prefetch is NEVER
// drained at the barrier; the compiler's counted vmcnt before ds_write covers it).
// LDS B chunk (n, kg) at element n*32 + ((kg + (n>>1))&3)*8 (XOR swizzle, 0 conflicts).
__global__ __launch_bounds__(256, 2) void k_energy(
    const __hip_bfloat16* __restrict__ Eb, const float* __restrict__ Ef,
    const __hip_bfloat16* __restrict__ W1T, const float* __restrict__ qpp,
    const __hip_bfloat16* __restrict__ Vwb, const float* __restrict__ Vwf,
    const int* __restrict__ flagp, const int* __restrict__ lens,
    float* __restrict__ energy) {
  __shared__ __align__(16) __hip_bfloat16 Bt[2][128 * 32];  // 2 x 8 KB
  __shared__ float qps[HH];
  __shared__ float Vs[HH];

  const int tid = threadIdx.x;
  const int wave = tid >> 6, lane = tid & 63;
  const int quad = lane >> 4, l16 = lane & 15;
  const int row0 = blockIdx.x * 128;  // tiles never straddle a batch
  const int b = row0 >> 11;
  if ((row0 & 2047) >= lens[b]) return;  // fully-masked tile: consumers ignore s>=len

  const int mode = *flagp;

  for (int i = tid; i < HH; i += 256) {
    qps[i] = qpp[(size_t)b * HH + i] + qpp[(size_t)(64 + b) * HH + i] +
             qpp[(size_t)(128 + b) * HH + i] + qpp[(size_t)(192 + b) * HH + i];
    Vs[i] = mode ? (float)Vwb[i] : Vwf[i];
  }

  // ---- A fragments -> registers (E read exactly once) ----
  // afr[rb][kt]: A[m = wave*32 + rb*16 + l16][k = kt*32 + quad*8 + j]
  short8 afr[2][16];
  {
    const size_t eBase = (size_t)row0 * HH + (size_t)(wave * 32 + l16) * HH + quad * 8;
    if (mode) {
      const __hip_bfloat16* pa = Eb + eBase;
#pragma unroll
      for (int kt = 0; kt < 16; ++kt) {
        afr[0][kt] = *(const short8*)(pa + kt * 32);
        afr[1][kt] = *(const short8*)(pa + 16 * HH + kt * 32);
      }
    } else {
      const float* pa = Ef + eBase;
#pragma unroll
      for (int kt = 0; kt < 16; ++kt) {
#pragma unroll
        for (int rb = 0; rb < 2; ++rb) {
          const float* p = pa + rb * 16 * HH + kt * 32;
          f32x4 x0 = *(const f32x4*)p;
          f32x4 x1 = *(const f32x4*)(p + 4);
          short8 v;
#pragma unroll
          for (int j = 0; j < 4; ++j) {
            v[j] = f2bf(x0[j]);
            v[j + 4] = f2bf(x1[j]);
          }
          afr[rb][kt] = v;
        }
      }
    }
  }

  // ---- B staging lane mapping (16B chunk (n, kg) per lane, swizzled slot = lane*16B) ----
  const int rs0 = wave * 32 + (lane >> 2);
  const int rs1 = rs0 + 16;
  const int kg0 = ((lane & 3) - (rs0 >> 1)) & 3;
  const int kg1 = ((lane & 3) - (rs1 >> 1)) & 3;
  const __hip_bfloat16* pb0 = W1T + (size_t)rs0 * HH + kg0 * 8;
  const __hip_bfloat16* pb1 = W1T + (size_t)rs1 * HH + kg1 * 8;
  const int wslot = wave * 1024 + lane * 8;

  // fragment read offsets: B[k=quad*8+j][n = cb*16 + l16]
  int offB[8];
#pragma unroll
  for (int cb = 0; cb < 8; ++cb) {
    int n = cb * 16 + l16;
    offB[cb] = n * 32 + (((quad + (n >> 1)) & 3) << 3);
  }

  // prologue: stage step 0 into buffer 0, prefetch step 1
  short8 bp0 = *(const short8*)(pb0);
  short8 bp1 = *(const short8*)(pb1);
  *(short8*)(&Bt[0][0] + wslot) = bp0;
  *(short8*)(&Bt[0][0] + wslot + 512) = bp1;
  bp0 = *(const short8*)(pb0 + 32);  // OFF(1)
  bp1 = *(const short8*)(pb1 + 32);
  __syncthreads();  // full drain once; covers qps/Vs + buffer-0 staging

  float eacc[2][4] = {{0.f, 0.f, 0.f, 0.f}, {0.f, 0.f, 0.f, 0.f}};

  for (int nc = 0; nc < 4; ++nc) {
    f32x4 acc[2][8];
#pragma unroll
    for (int rb = 0; rb < 2; ++rb)
#pragma unroll
      for (int cb = 0; cb < 8; ++cb) acc[rb][cb] = (f32x4){0.f, 0.f, 0.f, 0.f};

#pragma unroll
    for (int kt = 0; kt < 16; ++kt) {
      const int t = nc * 16 + kt;
      // compute step t from Bt[t&1]
      const __hip_bfloat16* bb = &Bt[t & 1][0];
      short8 af0 = afr[0][kt];
      short8 af1 = afr[1][kt];
#pragma unroll
      for (int cb = 0; cb < 8; ++cb) {
        short8 bf = *(const short8*)(bb + offB[cb]);
        acc[0][cb] = __builtin_amdgcn_mfma_f32_16x16x32_bf16(af0, bf, acc[0][cb], 0, 0, 0);
        acc[1][cb] = __builtin_amdgcn_mfma_f32_16x16x32_bf16(af1, bf, acc[1][cb], 0, 0, 0);
      }

      // stage step t+1 (data already in bp regs), prefetch step t+2
      {
        __hip_bfloat16* bw = &Bt[(t + 1) & 1][0] + wslot;
        *(short8*)bw = bp0;  // compiler inserts the counted vmcnt wait for bp here
        *(short8*)(bw + 512) = bp1;
        int t2 = t + 2;
        if (t2 > 63) t2 = 63;                          // redundant re-read on last steps
        int o = ((t2 >> 4) << 16) + ((t2 & 15) << 5);  // (t2>>4)*128*512 + (t2&15)*32
        bp0 = *(const short8*)(pb0 + o);               // prefetch (L2-resident)
        bp1 = *(const short8*)(pb1 + o);
      }
      // single barrier per kt-step: drain LDS only — global prefetch stays in flight
      asm volatile("s_waitcnt lgkmcnt(0)" ::: "memory");
      __builtin_amdgcn_s_barrier();
      __builtin_amdgcn_sched_barrier(0);
    }

    // epilogue: +qp, tanh, dot with V   (C/D: col=l16, row=quad*4+r)
#pragma unroll
    for (int rb = 0; rb < 2; ++rb)
#pragma unroll
      for (int cb = 0; cb < 8; ++cb) {
        int col = nc * 128 + cb * 16 + l16;
        float qv = qps[col], vv = Vs[col];
#pragma unroll
        for (int r = 0; r < 4; ++r) {
          float t = tanh_fast(acc[rb][cb][r] + qv);
          eacc[rb][r] = fmaf(vv, t, eacc[rb][r]);
        }
      }
  }

  // sum over the 16 column-groups held across l16 lanes, then write
#pragma unroll
  for (int rb = 0; rb < 2; ++rb)
#pragma unroll
    for (int r = 0; r < 4; ++r) {
      float v = eacc[rb][r];
#pragma unroll
      for (int o = 1; o < 16; o <<= 1) v += __shfl_xor(v, o);
      if (l16 == 0) energy[row0 + wave * 32 + rb * 16 + quad * 4 + r] = v;
    }
}

// ---------------- context partials: fused per-block softmax stats, no atomics ----------------
// 16 s-chunks of 128 rows per batch; each block recomputes the batch max/denominator
// from the L2-hot energy vector (8 KB) and writes a 512-wide partial.
__global__ __launch_bounds__(256) void k_ctx(const __hip_bfloat16* __restrict__ Eb,
                                             const float* __restrict__ Ef,
                                             const float* __restrict__ energy,
                                             const int* __restrict__ lens,
                                             const int* __restrict__ flagp,
                                             float* __restrict__ partials) {
  const int mode = *flagp;
  int bc = blockIdx.x;
  int b = bc >> 4, c = bc & 15;
  int len = lens[b];
  int s0 = c * 128;
  if (s0 >= len) return;  // block-uniform; k_store skips these chunks via lens
  int tid = threadIdx.x;
  const float* eb = energy + b * SS;

  // in-block softmax stats over s < len
  float m = -3.0e38f;
  for (int s = tid; s < len; s += 256) m = fmaxf(m, eb[s]);
#pragma unroll
  for (int o = 1; o < 64; o <<= 1) m = fmaxf(m, __shfl_xor(m, o));
  __shared__ float sm[4];
  __shared__ float sd[4];
  int wv = tid >> 6;
  if ((tid & 63) == 0) sm[wv] = m;
  __syncthreads();
  m = fmaxf(fmaxf(sm[0], sm[1]), fmaxf(sm[2], sm[3]));
  float ssum = 0.f;
  for (int s = tid; s < len; s += 256) ssum += __expf(eb[s] - m);
#pragma unroll
  for (int o = 1; o < 64; o <<= 1) ssum += __shfl_xor(ssum, o);
  if ((tid & 63) == 0) sd[wv] = ssum;
  __syncthreads();
  float inv = 1.f / (sd[0] + sd[1] + sd[2] + sd[3]);

  __shared__ float p[128];
  __shared__ f32x4 part[128];
  if (tid < 128) {
    int s = s0 + tid;
    p[tid] = (s < len) ? __expf(eb[s] - m) * inv : 0.f;
  }
  __syncthreads();
  int n = min(128, len - s0);
  int h0 = (tid & 127) * 4;
  int r = tid >> 7;  // 0/1: waves {0,1} take even rows, {2,3} odd
  f32x4 a = {0.f, 0.f, 0.f, 0.f};
  if (mode) {
    const __hip_bfloat16* base = Eb + (size_t)(b * SS + s0) * HH + h0;
#pragma unroll 2
    for (int i = r; i < n; i += 2) {
      float w = p[i];
      uint2 u = *(const uint2*)(base + (size_t)i * HH);
      a[0] = fmaf(w, bflo(u.x), a[0]);
      a[1] = fmaf(w, bfhi(u.x), a[1]);
      a[2] = fmaf(w, bflo(u.y), a[2]);
      a[3] = fmaf(w, bfhi(u.y), a[3]);
    }
  } else {
    const float* base = Ef + (size_t)(b * SS + s0) * HH + h0;
#pragma unroll 2
    for (int i = r; i < n; i += 2) {
      float w = p[i];
      f32x4 v = __builtin_nontemporal_load((const f32x4*)(base + (size_t)i * HH));
      a[0] = fmaf(w, v[0], a[0]);
      a[1] = fmaf(w, v[1], a[1]);
      a[2] = fmaf(w, v[2], a[2]);
      a[3] = fmaf(w, v[3], a[3]);
    }
  }
  if (tid >= 128) part[tid - 128] = a;
  __syncthreads();
  if (tid < 128) {
    f32x4 o = part[tid];
    f32x4 s;
    s[0] = a[0] + o[0];
    s[1] = a[1] + o[1];
    s[2] = a[2] + o[2];
    s[3] = a[3] + o[3];
    *(f32x4*)(partials + (size_t)(b * 16 + c) * HH + h0) = s;
  }
}

// ---------------- reduce valid chunks + store (dtype per flag) ----------------
__global__ __launch_bounds__(256) void k_store(const float* __restrict__ partials,
                                               const int* __restrict__ lens,
                                               const int* __restrict__ flagp,
                                               __hip_bfloat16* __restrict__ outb,
                                               float* __restrict__ outf) {
  const int mode = *flagp;
  int i = blockIdx.x * 256 + threadIdx.x;
  int b = i >> 9, h = i & 511;
  int nch = (lens[b] + 127) >> 7;  // only chunks that k_ctx actually wrote
  float s = 0.f;
  for (int c = 0; c < nch; ++c) s += partials[(size_t)(b * 16 + c) * HH + h];
  if (mode)
    outb[i] = __float2bfloat16(s);
  else
    outf[i] = s;
}

extern "C" void kernel_launch(void* const* d_in, const int* in_sizes, int n_in,
                              void* d_out, int out_size, void* d_ws, size_t ws_size,
                              hipStream_t stream) {
  const __hip_bfloat16* qb  = (const __hip_bfloat16*)d_in[0];
  const float*          qf  = (const float*)d_in[0];
  const __hip_bfloat16* Eb  = (const __hip_bfloat16*)d_in[1];
  const float*          Ef  = (const float*)d_in[1];
  const int* lens           = (const int*)d_in[2];
  const __hip_bfloat16* W1b = (const __hip_bfloat16*)d_in[3];
  const float*          W1f = (const float*)d_in[3];
  const __hip_bfloat16* W2b = (const __hip_bfloat16*)d_in[4];
  const float*          W2f = (const float*)d_in[4];
  const __hip_bfloat16* Vwb = (const __hip_bfloat16*)d_in[5];
  const float*          Vwf = (const float*)d_in[5];
  __hip_bfloat16* outb      = (__hip_bfloat16*)d_out;
  float*          outf      = (float*)d_out;

  char* ws = (char*)d_ws;
  float* energy       = (float*)(ws);                    // 512 KB
  __hip_bfloat16* W1T = (__hip_bfloat16*)(ws + 524288);  // 512 KB
  float* qp_part      = (float*)(ws + 1048576);          // 512 KB: [4][64][512]
  float* partials     = (float*)(ws + 1572864);          // 2 MB: [64][16][512]
  int* flag           = (int*)(ws + 3670016);            // 4 B

  k_detect<<<dim3(1), 64, 0, stream>>>((const unsigned*)d_in[1], flag);
  k_transpose<<<dim3(8, 8), 256, 0, stream>>>(W1b, W1f, flag, W1T);
  k_qp<<<dim3(64, 4), 256, 0, stream>>>(qb, qf, W2b, W2f, flag, qp_part);
  k_energy<<<dim3(1024), 256, 0, stream>>>(Eb, Ef, W1T, qp_part, Vwb, Vwf, flag, lens, energy);
  k_ctx<<<dim3(1024), 256, 0, stream>>>(Eb, Ef, energy, lens, flag, partials);
  k_store<<<dim3(128), 256, 0, stream>>>(partials, lens, flag, outb, outf);
}

// Round 3
// 466.483 us; speedup vs baseline: 1.0373x; 1.0310x over previous
//
#include <hip/hip_runtime.h>
#include <hip/hip_bf16.h>

#define SS 2048
#define HH 512

typedef __attribute__((ext_vector_type(8))) short short8;
typedef __attribute__((ext_vector_type(4))) float f32x4;

__device__ __forceinline__ float bflo(unsigned u) { return __uint_as_float(u << 16); }
__device__ __forceinline__ float bfhi(unsigned u) { return __uint_as_float(u & 0xffff0000u); }

__device__ __forceinline__ short f2bf(float v) {
  __hip_bfloat16 h = __float2bfloat16(v);
  return *reinterpret_cast<short*>(&h);
}

__device__ __forceinline__ float tanh_fast(float x) {
  x = fminf(fmaxf(x, -15.f), 15.f);
  float e = __expf(2.f * x);
  return 1.f - 2.f / (e + 1.f);
}

// ---------------- dtype detector: 1 = inputs are bf16, 0 = fp32 ----------------
__global__ void k_detect(const unsigned* __restrict__ Eu, int* __restrict__ flag) {
  int lane = threadIdx.x;  // 64 threads
  unsigned w = Eu[(size_t)lane * 4097];
  unsigned e = (w >> 7) & 0xFF;  // exponent field of the low bf16 half
  bool inr = (e >= 90 && e <= 140);
  unsigned long long m = __ballot(inr);
  if (lane == 0) *flag = (__popcll(m) >= 48) ? 1 : 0;
}

// ---------------- prep: blocks 0..63 transpose W1 -> W1T; blocks 64..319 qp partials ----------------
__global__ __launch_bounds__(256) void k_prep(const __hip_bfloat16* __restrict__ W1b,
                                              const float* __restrict__ W1f,
                                              const __hip_bfloat16* __restrict__ qb,
                                              const float* __restrict__ qf,
                                              const __hip_bfloat16* __restrict__ W2b,
                                              const float* __restrict__ W2f,
                                              const int* __restrict__ flagp,
                                              __hip_bfloat16* __restrict__ W1T,
                                              float* __restrict__ qp_part) {
  const int mode = *flagp;
  __shared__ __hip_bfloat16 t[64][65];
  __shared__ float qs[128];
  if (blockIdx.x < 64) {
    // ---- W1 transpose tile: W1T[d][h] = W1[h][d] ----
    int r0 = (blockIdx.x >> 3) * 64, c0 = (blockIdx.x & 7) * 64;
    for (int i = threadIdx.x; i < 4096; i += 256) {
      int r = i >> 6, c = i & 63;
      size_t idx = (size_t)(r0 + r) * HH + c0 + c;
      float v = mode ? (float)W1b[idx] : W1f[idx];
      t[r][c] = __float2bfloat16(v);
    }
    __syncthreads();
    for (int i = threadIdx.x; i < 4096; i += 256) {
      int r = i >> 6, c = i & 63;
      W1T[(size_t)(c0 + r) * HH + r0 + c] = t[c][r];
    }
  } else {
    // ---- qp_part[p][b][d] = sum_{h in part p} q[b][h] * W2[h][d] ----
    int bx = blockIdx.x - 64;
    int b = bx & 63, p = bx >> 6, h0 = p * 128;
    if (threadIdx.x < 128) {
      size_t qi = (size_t)b * HH + h0 + threadIdx.x;
      qs[threadIdx.x] = mode ? (float)qb[qi] : qf[qi];
    }
    __syncthreads();
    int col = threadIdx.x * 2;
    float a0 = 0.f, a1 = 0.f;
    if (mode) {
#pragma unroll 4
      for (int i = 0; i < 128; ++i) {
        float qa = qs[i];
        unsigned u = *(const unsigned*)(W2b + (size_t)(h0 + i) * HH + col);
        a0 = fmaf(qa, bflo(u), a0);
        a1 = fmaf(qa, bfhi(u), a1);
      }
    } else {
#pragma unroll 4
      for (int i = 0; i < 128; ++i) {
        float qa = qs[i];
        float2 v = *(const float2*)(W2f + (size_t)(h0 + i) * HH + col);
        a0 = fmaf(qa, v.x, a0);
        a1 = fmaf(qa, v.y, a1);
      }
    }
    float* dst = qp_part + ((size_t)p * 64 + b) * HH + col;
    dst[0] = a0;
    dst[1] = a1;
  }
}

// ---------------- fused energy + tile-local softmax + PV partial ----------------
// Per 128-row tile: e = V.tanh(E*W1 + qp) via MFMA (B double-buffered in LDS,
// register-prefetched, one lgkmcnt-only barrier per kt-step); then tile softmax
// (m_t, d_t, weights in LDS); then PV partial ctx re-reading the block's own
// E-slab (L2/L3-hot: it was read ~5-10us earlier this kernel). Writes
// tpart[tile] = {512 x ctx_part, m_t, d_t}. Split-K flash-attention scheme.
__global__ __launch_bounds__(256, 2) void k_energy(
    const __hip_bfloat16* __restrict__ Eb, const float* __restrict__ Ef,
    const __hip_bfloat16* __restrict__ W1T, const float* __restrict__ qpp,
    const __hip_bfloat16* __restrict__ Vwb, const float* __restrict__ Vwf,
    const int* __restrict__ flagp, const int* __restrict__ lens,
    float* __restrict__ tpart) {
  __shared__ __align__(16) __hip_bfloat16 Bt[2][128 * 32];  // 2 x 8 KB
  __shared__ float qps[HH];
  __shared__ float Vs[HH];
  __shared__ float p[128];
  __shared__ float red[4];
  __shared__ f32x4 part[128];

  const int tid = threadIdx.x;
  const int wave = tid >> 6, lane = tid & 63;
  const int quad = lane >> 4, l16 = lane & 15;
  const int row0 = blockIdx.x * 128;  // tiles never straddle a batch
  const int b = row0 >> 11;
  const int len = lens[b];
  if ((row0 & 2047) >= len) return;  // fully-masked tile: k_reduce skips via lens

  const int mode = *flagp;

  for (int i = tid; i < HH; i += 256) {
    qps[i] = qpp[(size_t)b * HH + i] + qpp[(size_t)(64 + b) * HH + i] +
             qpp[(size_t)(128 + b) * HH + i] + qpp[(size_t)(192 + b) * HH + i];
    Vs[i] = mode ? (float)Vwb[i] : Vwf[i];
  }

  // ---- A fragments -> registers ----
  // afr[rb][kt]: A[m = wave*32 + rb*16 + l16][k = kt*32 + quad*8 + j]
  short8 afr[2][16];
  {
    const size_t eBase = (size_t)row0 * HH + (size_t)(wave * 32 + l16) * HH + quad * 8;
    if (mode) {
      const __hip_bfloat16* pa = Eb + eBase;
#pragma unroll
      for (int kt = 0; kt < 16; ++kt) {
        afr[0][kt] = *(const short8*)(pa + kt * 32);
        afr[1][kt] = *(const short8*)(pa + 16 * HH + kt * 32);
      }
    } else {
      const float* pa = Ef + eBase;
#pragma unroll
      for (int kt = 0; kt < 16; ++kt) {
#pragma unroll
        for (int rb = 0; rb < 2; ++rb) {
          const float* pp = pa + rb * 16 * HH + kt * 32;
          f32x4 x0 = *(const f32x4*)pp;
          f32x4 x1 = *(const f32x4*)(pp + 4);
          short8 v;
#pragma unroll
          for (int j = 0; j < 4; ++j) {
            v[j] = f2bf(x0[j]);
            v[j + 4] = f2bf(x1[j]);
          }
          afr[rb][kt] = v;
        }
      }
    }
  }

  // ---- B staging lane mapping (16B chunk (n, kg) per lane, swizzled slot = lane*16B) ----
  const int rs0 = wave * 32 + (lane >> 2);
  const int rs1 = rs0 + 16;
  const int kg0 = ((lane & 3) - (rs0 >> 1)) & 3;
  const int kg1 = ((lane & 3) - (rs1 >> 1)) & 3;
  const __hip_bfloat16* pb0 = W1T + (size_t)rs0 * HH + kg0 * 8;
  const __hip_bfloat16* pb1 = W1T + (size_t)rs1 * HH + kg1 * 8;
  const int wslot = wave * 1024 + lane * 8;

  // fragment read offsets: B[k=quad*8+j][n = cb*16 + l16]
  int offB[8];
#pragma unroll
  for (int cb = 0; cb < 8; ++cb) {
    int n = cb * 16 + l16;
    offB[cb] = n * 32 + (((quad + (n >> 1)) & 3) << 3);
  }

  // prologue: stage step 0 into buffer 0, prefetch step 1
  short8 bp0 = *(const short8*)(pb0);
  short8 bp1 = *(const short8*)(pb1);
  *(short8*)(&Bt[0][0] + wslot) = bp0;
  *(short8*)(&Bt[0][0] + wslot + 512) = bp1;
  bp0 = *(const short8*)(pb0 + 32);  // OFF(1)
  bp1 = *(const short8*)(pb1 + 32);
  __syncthreads();  // full drain once; covers qps/Vs + buffer-0 staging

  float eacc[2][4] = {{0.f, 0.f, 0.f, 0.f}, {0.f, 0.f, 0.f, 0.f}};

  for (int nc = 0; nc < 4; ++nc) {
    f32x4 acc[2][8];
#pragma unroll
    for (int rb = 0; rb < 2; ++rb)
#pragma unroll
      for (int cb = 0; cb < 8; ++cb) acc[rb][cb] = (f32x4){0.f, 0.f, 0.f, 0.f};

#pragma unroll
    for (int kt = 0; kt < 16; ++kt) {
      const int t = nc * 16 + kt;
      // compute step t from Bt[t&1]
      const __hip_bfloat16* bb = &Bt[t & 1][0];
      short8 af0 = afr[0][kt];
      short8 af1 = afr[1][kt];
#pragma unroll
      for (int cb = 0; cb < 8; ++cb) {
        short8 bf = *(const short8*)(bb + offB[cb]);
        acc[0][cb] = __builtin_amdgcn_mfma_f32_16x16x32_bf16(af0, bf, acc[0][cb], 0, 0, 0);
        acc[1][cb] = __builtin_amdgcn_mfma_f32_16x16x32_bf16(af1, bf, acc[1][cb], 0, 0, 0);
      }

      // stage step t+1 (data already in bp regs), prefetch step t+2
      {
        __hip_bfloat16* bw = &Bt[(t + 1) & 1][0] + wslot;
        *(short8*)bw = bp0;  // compiler inserts the counted vmcnt wait for bp here
        *(short8*)(bw + 512) = bp1;
        int t2 = t + 2;
        if (t2 > 63) t2 = 63;                          // redundant re-read on last steps
        int o = ((t2 >> 4) << 16) + ((t2 & 15) << 5);  // (t2>>4)*128*512 + (t2&15)*32
        bp0 = *(const short8*)(pb0 + o);               // prefetch (L2-resident)
        bp1 = *(const short8*)(pb1 + o);
      }
      // single barrier per kt-step: drain LDS only — global prefetch stays in flight
      asm volatile("s_waitcnt lgkmcnt(0)" ::: "memory");
      __builtin_amdgcn_s_barrier();
      __builtin_amdgcn_sched_barrier(0);
    }

    // epilogue: +qp, tanh, dot with V   (C/D: col=l16, row=quad*4+r)
#pragma unroll
    for (int rb = 0; rb < 2; ++rb)
#pragma unroll
      for (int cb = 0; cb < 8; ++cb) {
        int col = nc * 128 + cb * 16 + l16;
        float qv = qps[col], vv = Vs[col];
#pragma unroll
        for (int r = 0; r < 4; ++r) {
          float tv = tanh_fast(acc[rb][cb][r] + qv);
          eacc[rb][r] = fmaf(vv, tv, eacc[rb][r]);
        }
      }
  }

  // ---- energies -> LDS (masked rows get -inf) ----
#pragma unroll
  for (int rb = 0; rb < 2; ++rb)
#pragma unroll
    for (int r = 0; r < 4; ++r) {
      float v = eacc[rb][r];
#pragma unroll
      for (int o = 1; o < 16; o <<= 1) v += __shfl_xor(v, o);
      if (l16 == 0) {
        int row = wave * 32 + rb * 16 + quad * 4 + r;
        int s = (row0 & 2047) + row;
        p[row] = (s < len) ? v : -3.0e38f;
      }
    }
  __syncthreads();

  // ---- tile-local softmax: m_t, d_t, weights -> p[] ----
  float e = (tid < 128) ? p[tid] : -3.0e38f;
  float m = e;
#pragma unroll
  for (int o = 1; o < 64; o <<= 1) m = fmaxf(m, __shfl_xor(m, o));
  if ((tid & 63) == 0) red[tid >> 6] = m;
  __syncthreads();
  m = fmaxf(fmaxf(red[0], red[1]), fmaxf(red[2], red[3]));
  float w = (tid < 128) ? __expf(e - m) : 0.f;
  float d = w;
#pragma unroll
  for (int o = 1; o < 64; o <<= 1) d += __shfl_xor(d, o);
  __syncthreads();  // red reuse
  if ((tid & 63) == 0) red[tid >> 6] = d;
  if (tid < 128) p[tid] = w;
  __syncthreads();
  const float d_t = red[0] + red[1] + red[2] + red[3];

  // ---- PV partial: ctx_part[h] = sum_{s in tile} w_s * E[s][h] (E slab is cache-hot) ----
  const int n = min(128, len - (row0 & 2047));
  const int h0 = (tid & 127) * 4;
  const int rr = tid >> 7;  // 0/1: waves {0,1} take even rows, {2,3} odd
  f32x4 a = {0.f, 0.f, 0.f, 0.f};
  if (mode) {
    const __hip_bfloat16* base = Eb + (size_t)row0 * HH + h0;
#pragma unroll 2
    for (int i = rr; i < n; i += 2) {
      float wv = p[i];
      uint2 u = *(const uint2*)(base + (size_t)i * HH);
      a[0] = fmaf(wv, bflo(u.x), a[0]);
      a[1] = fmaf(wv, bfhi(u.x), a[1]);
      a[2] = fmaf(wv, bflo(u.y), a[2]);
      a[3] = fmaf(wv, bfhi(u.y), a[3]);
    }
  } else {
    const float* base = Ef + (size_t)row0 * HH + h0;
#pragma unroll 2
    for (int i = rr; i < n; i += 2) {
      float wv = p[i];
      f32x4 v = *(const f32x4*)(base + (size_t)i * HH);
      a[0] = fmaf(wv, v[0], a[0]);
      a[1] = fmaf(wv, v[1], a[1]);
      a[2] = fmaf(wv, v[2], a[2]);
      a[3] = fmaf(wv, v[3], a[3]);
    }
  }
  if (tid >= 128) part[tid - 128] = a;
  __syncthreads();
  if (tid < 128) {
    f32x4 o = part[tid];
    f32x4 s;
    s[0] = a[0] + o[0];
    s[1] = a[1] + o[1];
    s[2] = a[2] + o[2];
    s[3] = a[3] + o[3];
    *(f32x4*)(tpart + (size_t)blockIdx.x * 516 + h0) = s;
  }
  if (tid == 0) {
    tpart[(size_t)blockIdx.x * 516 + 512] = m;
    tpart[(size_t)blockIdx.x * 516 + 513] = d_t;
  }
}

// ---------------- per-batch reduce of tile partials + store ----------------
__global__ __launch_bounds__(256) void k_reduce(const float* __restrict__ tpart,
                                                const int* __restrict__ lens,
                                                const int* __restrict__ flagp,
                                                __hip_bfloat16* __restrict__ outb,
                                                float* __restrict__ outf) {
  const int b = blockIdx.x, tid = threadIdx.x;
  const int nch = (lens[b] + 127) >> 7;  // only tiles k_energy actually wrote
  const float* tb = tpart + (size_t)b * 16 * 516;
  float m = -3.0e38f;
  for (int c = 0; c < nch; ++c) m = fmaxf(m, tb[c * 516 + 512]);
  const int h = tid * 2;
  float den = 0.f, a0 = 0.f, a1 = 0.f;
  for (int c = 0; c < nch; ++c) {
    float sc = __expf(tb[c * 516 + 512] - m);
    den = fmaf(tb[c * 516 + 513], sc, den);
    float2 v = *(const float2*)(tb + c * 516 + h);
    a0 = fmaf(sc, v.x, a0);
    a1 = fmaf(sc, v.y, a1);
  }
  float inv = 1.f / den;
  int i = b * HH + h;
  if (*flagp) {
    outb[i] = __float2bfloat16(a0 * inv);
    outb[i + 1] = __float2bfloat16(a1 * inv);
  } else {
    outf[i] = a0 * inv;
    outf[i + 1] = a1 * inv;
  }
}

extern "C" void kernel_launch(void* const* d_in, const int* in_sizes, int n_in,
                              void* d_out, int out_size, void* d_ws, size_t ws_size,
                              hipStream_t stream) {
  const __hip_bfloat16* qb  = (const __hip_bfloat16*)d_in[0];
  const float*          qf  = (const float*)d_in[0];
  const __hip_bfloat16* Eb  = (const __hip_bfloat16*)d_in[1];
  const float*          Ef  = (const float*)d_in[1];
  const int* lens           = (const int*)d_in[2];
  const __hip_bfloat16* W1b = (const __hip_bfloat16*)d_in[3];
  const float*          W1f = (const float*)d_in[3];
  const __hip_bfloat16* W2b = (const __hip_bfloat16*)d_in[4];
  const float*          W2f = (const float*)d_in[4];
  const __hip_bfloat16* Vwb = (const __hip_bfloat16*)d_in[5];
  const float*          Vwf = (const float*)d_in[5];
  __hip_bfloat16* outb      = (__hip_bfloat16*)d_out;
  float*          outf      = (float*)d_out;

  char* ws = (char*)d_ws;
  __hip_bfloat16* W1T = (__hip_bfloat16*)(ws);           // 512 KB
  float* qp_part      = (float*)(ws + 524288);           // 512 KB: [4][64][512]
  float* tpart        = (float*)(ws + 1048576);          // ~2.02 MB: [1024][516]
  int* flag           = (int*)(ws + 3162112);            // 4 B

  k_detect<<<dim3(1), 64, 0, stream>>>((const unsigned*)d_in[1], flag);
  k_prep<<<dim3(320), 256, 0, stream>>>(W1b, W1f, qb, qf, W2b, W2f, flag, W1T, qp_part);
  k_energy<<<dim3(1024), 256, 0, stream>>>(Eb, Ef, W1T, qp_part, Vwb, Vwf, flag, lens, tpart);
  k_reduce<<<dim3(64), 256, 0, stream>>>(tpart, lens, flag, outb, outf);
}